// Round 1
// baseline (6434.484 us; speedup 1.0000x reference)
//
#include <hip/hip_runtime.h>
#include <hip/hip_bf16.h>
#include <math.h>

#define GN 100000
#define GE 3200000
#define GNG 16
#define GF 512
#define GDT 8

// ---------------- ws layout (bytes) ----------------
// 0      : double stats0[32]   (sum[16], sumsq[16])
// 256    : double stats1[32]
// 512    : double stats2[16]   (sum[8], sumsq[8])
// 640    : float  sb0[32]      (scale[16], bias[16])
// 768    : float  sb1[32]
// 896    : float  sb2[16]
// 960    : unsigned pools[3*128]  (monotonic-mapped float max)
// 4096   : float pre[GN*16]    (reused as [GN*8] in layer 2)
// 4096+6400000  : float hbuf[GN*16]
// 4096+12800000 : float agg[GN*16]
// total ~19.2 MB

__device__ __forceinline__ float geluf(float x) {
    // exact GELU: 0.5*x*(1+erf(x/sqrt(2)))
    return 0.5f * x * (1.0f + erff(x * 0.70710678118654752440f));
}
// monotonic float<->uint mapping for atomicMax on floats (handles negatives)
__device__ __forceinline__ unsigned fmap(float f) {
    unsigned u = __float_as_uint(f);
    return (u & 0x80000000u) ? ~u : (u | 0x80000000u);
}
__device__ __forceinline__ float funmap(unsigned u) {
    return __uint_as_float((u & 0x80000000u) ? (u ^ 0x80000000u) : ~u);
}

// -------- init: zero stats, init pools to mapped(-inf), zero agg --------
__global__ void k_init(double* __restrict__ stats, unsigned* __restrict__ pools,
                       float* __restrict__ agg) {
    int i = blockIdx.x * blockDim.x + threadIdx.x;
    if (i < 80) stats[i] = 0.0;
    if (i < 3 * 128) pools[i] = 0x007FFFFFu;  // fmap(-inf)
    int stride = gridDim.x * blockDim.x;
    for (int j = i; j < GN * 16; j += stride) agg[j] = 0.0f;
}

// -------- wave-reduce per-column sum/sumsq into double stats --------
template <int C>
__device__ __forceinline__ void stats_reduce(const float* acc, double* stats, int lane) {
#pragma unroll
    for (int j = 0; j < C; ++j) {
        float s = acc[j];
        float q = acc[j] * acc[j];
#pragma unroll
        for (int o = 32; o > 0; o >>= 1) {
            s += __shfl_down(s, o);
            q += __shfl_down(q, o);
        }
        if (lane == 0) {
            atomicAdd(&stats[j], (double)s);
            atomicAdd(&stats[C + j], (double)q);
        }
    }
}

// -------- layer 0 GEMM: pre = x@W0 + b0, accumulate BN stats --------
extern "C" __global__ void __launch_bounds__(256)
k_gemm0(const float* __restrict__ x, const float* __restrict__ W,
        const float* __restrict__ b, float* __restrict__ pre,
        double* __restrict__ stats) {
    int r = blockIdx.x * 256 + threadIdx.x;
    bool act = r < GN;
    float acc[16];
#pragma unroll
    for (int j = 0; j < 16; ++j) acc[j] = act ? b[j] : 0.0f;
    if (act) {
        const float4* xr = (const float4*)(x + (size_t)r * GF);
#pragma unroll 8
        for (int kk = 0; kk < GF / 4; ++kk) {
            float4 xv = xr[kk];
            float xa[4] = {xv.x, xv.y, xv.z, xv.w};
#pragma unroll
            for (int d = 0; d < 4; ++d) {
                const float* wr = W + (kk * 4 + d) * 16;  // wave-uniform -> s_load
#pragma unroll
                for (int j = 0; j < 16; ++j) acc[j] = fmaf(xa[d], wr[j], acc[j]);
            }
        }
        float4* pr = (float4*)(pre + (size_t)r * 16);
        pr[0] = make_float4(acc[0], acc[1], acc[2], acc[3]);
        pr[1] = make_float4(acc[4], acc[5], acc[6], acc[7]);
        pr[2] = make_float4(acc[8], acc[9], acc[10], acc[11]);
        pr[3] = make_float4(acc[12], acc[13], acc[14], acc[15]);
    }
    stats_reduce<16>(acc, stats, threadIdx.x & 63);
}

// -------- finalize BN: scale = g/sqrt(var+eps), bias = be - mu*scale --------
extern "C" __global__ void k_stats(const double* __restrict__ stats,
                                   const float* __restrict__ g,
                                   const float* __restrict__ be,
                                   float* __restrict__ sb, int C) {
    int j = threadIdx.x;
    if (j >= C) return;
    double mu = stats[j] * (1.0 / GN);
    double var = stats[C + j] * (1.0 / GN) - mu * mu;
    float scale = g[j] / sqrtf((float)var + 1e-5f);
    sb[j] = scale;
    sb[C + j] = be[j] - (float)mu * scale;
}

// -------- shared pool helper: wave-max then atomicMax --------
__device__ __forceinline__ void pool_max(const float* z, bool act, int grp,
                                         unsigned* __restrict__ pool, int lane) {
    float mz[8];
#pragma unroll
    for (int jo = 0; jo < 8; ++jo) mz[jo] = act ? z[jo] : -INFINITY;
    int gl = __shfl(grp, 0);
    if (__all(grp == gl)) {
#pragma unroll
        for (int jo = 0; jo < 8; ++jo) {
            float m = mz[jo];
#pragma unroll
            for (int o = 32; o > 0; o >>= 1) m = fmaxf(m, __shfl_down(m, o));
            if (lane == 0) atomicMax(&pool[gl * 8 + jo], fmap(m));
        }
    } else {
        if (act) {
#pragma unroll
            for (int jo = 0; jo < 8; ++jo) atomicMax(&pool[grp * 8 + jo], fmap(mz[jo]));
        }
    }
}

// -------- layer 0 apply: h=GELU(BN(pre)); z=GELU(h@Wl0+bl0); zsum=z; pool --------
extern "C" __global__ void __launch_bounds__(256)
k_apply0(const float* __restrict__ pre, const float* __restrict__ sb,
         const float* __restrict__ Wl, const float* __restrict__ bl,
         const int* __restrict__ batch, float* __restrict__ h,
         float* __restrict__ zsum, unsigned* __restrict__ pool) {
    int r0 = blockIdx.x * 256 + threadIdx.x;
    bool act = r0 < GN;
    int r = act ? r0 : (GN - 1);
    const float4* pr = (const float4*)(pre + (size_t)r * 16);
    float4 p0 = pr[0], p1 = pr[1], p2 = pr[2], p3 = pr[3];
    float pv[16] = {p0.x, p0.y, p0.z, p0.w, p1.x, p1.y, p1.z, p1.w,
                    p2.x, p2.y, p2.z, p2.w, p3.x, p3.y, p3.z, p3.w};
    float hv[16];
#pragma unroll
    for (int j = 0; j < 16; ++j) hv[j] = geluf(fmaf(pv[j], sb[j], sb[16 + j]));
    if (act) {
        float4* hr = (float4*)(h + (size_t)r * 16);
        hr[0] = make_float4(hv[0], hv[1], hv[2], hv[3]);
        hr[1] = make_float4(hv[4], hv[5], hv[6], hv[7]);
        hr[2] = make_float4(hv[8], hv[9], hv[10], hv[11]);
        hr[3] = make_float4(hv[12], hv[13], hv[14], hv[15]);
    }
    float z[8];
#pragma unroll
    for (int jo = 0; jo < 8; ++jo) {
        float a = bl[jo];
#pragma unroll
        for (int j = 0; j < 16; ++j) a = fmaf(hv[j], Wl[j * 8 + jo], a);
        z[jo] = geluf(a);
    }
    if (act) {
        float4* zr = (float4*)(zsum + (size_t)r * 8);
        zr[0] = make_float4(z[0], z[1], z[2], z[3]);
        zr[1] = make_float4(z[4], z[5], z[6], z[7]);
    }
    pool_max(z, act, batch[r], pool, threadIdx.x & 63);
}

// -------- edge aggregation: agg[dst] += h[src] --------
extern "C" __global__ void __launch_bounds__(256)
k_edge(const int* __restrict__ src, const int* __restrict__ dst,
       const float* __restrict__ h, float* __restrict__ agg) {
    int e = blockIdx.x * 256 + threadIdx.x;
    if (e >= GE) return;
    int s = src[e], d = dst[e];
    const float4* hs = (const float4*)(h + (size_t)s * 16);
    float4 a = hs[0], b4 = hs[1], c = hs[2], w = hs[3];
    float* ad = agg + (size_t)d * 16;
    atomicAdd(ad + 0, a.x);  atomicAdd(ad + 1, a.y);
    atomicAdd(ad + 2, a.z);  atomicAdd(ad + 3, a.w);
    atomicAdd(ad + 4, b4.x); atomicAdd(ad + 5, b4.y);
    atomicAdd(ad + 6, b4.z); atomicAdd(ad + 7, b4.w);
    atomicAdd(ad + 8, c.x);  atomicAdd(ad + 9, c.y);
    atomicAdd(ad + 10, c.z); atomicAdd(ad + 11, c.w);
    atomicAdd(ad + 12, w.x); atomicAdd(ad + 13, w.y);
    atomicAdd(ad + 14, w.z); atomicAdd(ad + 15, w.w);
}

// -------- layer 1 GEMM: pre = (h+agg)@W1 + b1, stats --------
extern "C" __global__ void __launch_bounds__(256)
k_gemm1(const float* __restrict__ h, const float* __restrict__ agg,
        const float* __restrict__ W, const float* __restrict__ b,
        float* __restrict__ pre, double* __restrict__ stats) {
    int r = blockIdx.x * 256 + threadIdx.x;
    bool act = r < GN;
    float acc[16];
#pragma unroll
    for (int j = 0; j < 16; ++j) acc[j] = act ? b[j] : 0.0f;
    if (act) {
        const float4* hr = (const float4*)(h + (size_t)r * 16);
        const float4* ar = (const float4*)(agg + (size_t)r * 16);
        float t[16];
#pragma unroll
        for (int c = 0; c < 4; ++c) {
            float4 u = hr[c], v = ar[c];
            t[c * 4 + 0] = u.x + v.x; t[c * 4 + 1] = u.y + v.y;
            t[c * 4 + 2] = u.z + v.z; t[c * 4 + 3] = u.w + v.w;
        }
#pragma unroll
        for (int k = 0; k < 16; ++k)
#pragma unroll
            for (int j = 0; j < 16; ++j) acc[j] = fmaf(t[k], W[k * 16 + j], acc[j]);
        float4* pr = (float4*)(pre + (size_t)r * 16);
        pr[0] = make_float4(acc[0], acc[1], acc[2], acc[3]);
        pr[1] = make_float4(acc[4], acc[5], acc[6], acc[7]);
        pr[2] = make_float4(acc[8], acc[9], acc[10], acc[11]);
        pr[3] = make_float4(acc[12], acc[13], acc[14], acc[15]);
    }
    stats_reduce<16>(acc, stats, threadIdx.x & 63);
}

// -------- layer 1 apply: h=BN(pre); z=h@Wl1+bl1; zsum+=z; pool; zero agg --------
extern "C" __global__ void __launch_bounds__(256)
k_apply1(const float* __restrict__ pre, const float* __restrict__ sb,
         const float* __restrict__ Wl, const float* __restrict__ bl,
         const int* __restrict__ batch, float* __restrict__ h,
         float* __restrict__ zsum, unsigned* __restrict__ pool,
         float* __restrict__ agg) {
    int r0 = blockIdx.x * 256 + threadIdx.x;
    bool act = r0 < GN;
    int r = act ? r0 : (GN - 1);
    const float4* pr = (const float4*)(pre + (size_t)r * 16);
    float4 p0 = pr[0], p1 = pr[1], p2 = pr[2], p3 = pr[3];
    float pv[16] = {p0.x, p0.y, p0.z, p0.w, p1.x, p1.y, p1.z, p1.w,
                    p2.x, p2.y, p2.z, p2.w, p3.x, p3.y, p3.z, p3.w};
    float hv[16];
#pragma unroll
    for (int j = 0; j < 16; ++j) hv[j] = fmaf(pv[j], sb[j], sb[16 + j]);
    if (act) {
        float4* hr = (float4*)(h + (size_t)r * 16);
        hr[0] = make_float4(hv[0], hv[1], hv[2], hv[3]);
        hr[1] = make_float4(hv[4], hv[5], hv[6], hv[7]);
        hr[2] = make_float4(hv[8], hv[9], hv[10], hv[11]);
        hr[3] = make_float4(hv[12], hv[13], hv[14], hv[15]);
        // zero agg for layer-2 edge pass
        float4* ar = (float4*)(agg + (size_t)r * 16);
        float4 zf = make_float4(0.f, 0.f, 0.f, 0.f);
        ar[0] = zf; ar[1] = zf; ar[2] = zf; ar[3] = zf;
    }
    float z[8];
#pragma unroll
    for (int jo = 0; jo < 8; ++jo) {
        float a = bl[jo];
#pragma unroll
        for (int j = 0; j < 16; ++j) a = fmaf(hv[j], Wl[j * 8 + jo], a);
        z[jo] = a;
    }
    if (act) {
        float4* zr = (float4*)(zsum + (size_t)r * 8);
        float4 z0 = zr[0], z1 = zr[1];
        zr[0] = make_float4(z0.x + z[0], z0.y + z[1], z0.z + z[2], z0.w + z[3]);
        zr[1] = make_float4(z1.x + z[4], z1.y + z[5], z1.z + z[6], z1.w + z[7]);
    }
    pool_max(z, act, batch[r], pool, threadIdx.x & 63);
}

// -------- layer 2 GEMM: pre8 = (h+agg)@W2 + b2, stats (C=8) --------
extern "C" __global__ void __launch_bounds__(256)
k_gemm2(const float* __restrict__ h, const float* __restrict__ agg,
        const float* __restrict__ W, const float* __restrict__ b,
        float* __restrict__ pre, double* __restrict__ stats) {
    int r = blockIdx.x * 256 + threadIdx.x;
    bool act = r < GN;
    float acc[8];
#pragma unroll
    for (int j = 0; j < 8; ++j) acc[j] = act ? b[j] : 0.0f;
    if (act) {
        const float4* hr = (const float4*)(h + (size_t)r * 16);
        const float4* ar = (const float4*)(agg + (size_t)r * 16);
        float t[16];
#pragma unroll
        for (int c = 0; c < 4; ++c) {
            float4 u = hr[c], v = ar[c];
            t[c * 4 + 0] = u.x + v.x; t[c * 4 + 1] = u.y + v.y;
            t[c * 4 + 2] = u.z + v.z; t[c * 4 + 3] = u.w + v.w;
        }
#pragma unroll
        for (int k = 0; k < 16; ++k)
#pragma unroll
            for (int j = 0; j < 8; ++j) acc[j] = fmaf(t[k], W[k * 8 + j], acc[j]);
        float4* pr = (float4*)(pre + (size_t)r * 8);
        pr[0] = make_float4(acc[0], acc[1], acc[2], acc[3]);
        pr[1] = make_float4(acc[4], acc[5], acc[6], acc[7]);
    }
    stats_reduce<8>(acc, stats, threadIdx.x & 63);
}

// -------- layer 2 apply: h=BN(pre8) -> d_out; z=h@Wl2+bl2; zsum+=z; pool --------
extern "C" __global__ void __launch_bounds__(256)
k_apply2(const float* __restrict__ pre, const float* __restrict__ sb,
         const float* __restrict__ Wl, const float* __restrict__ bl,
         const int* __restrict__ batch, float* __restrict__ hout,
         float* __restrict__ zsum, unsigned* __restrict__ pool) {
    int r0 = blockIdx.x * 256 + threadIdx.x;
    bool act = r0 < GN;
    int r = act ? r0 : (GN - 1);
    const float4* pr = (const float4*)(pre + (size_t)r * 8);
    float4 p0 = pr[0], p1 = pr[1];
    float pv[8] = {p0.x, p0.y, p0.z, p0.w, p1.x, p1.y, p1.z, p1.w};
    float hv[8];
#pragma unroll
    for (int j = 0; j < 8; ++j) hv[j] = fmaf(pv[j], sb[j], sb[8 + j]);
    if (act) {
        float4* hr = (float4*)(hout + (size_t)r * 8);
        hr[0] = make_float4(hv[0], hv[1], hv[2], hv[3]);
        hr[1] = make_float4(hv[4], hv[5], hv[6], hv[7]);
    }
    float z[8];
#pragma unroll
    for (int jo = 0; jo < 8; ++jo) {
        float a = bl[jo];
#pragma unroll
        for (int j = 0; j < 8; ++j) a = fmaf(hv[j], Wl[j * 8 + jo], a);
        z[jo] = a;
    }
    if (act) {
        float4* zr = (float4*)(zsum + (size_t)r * 8);
        float4 z0 = zr[0], z1 = zr[1];
        zr[0] = make_float4(z0.x + z[0], z0.y + z[1], z0.z + z[2], z0.w + z[3]);
        zr[1] = make_float4(z1.x + z[4], z1.y + z[5], z1.z + z[6], z1.w + z[7]);
    }
    pool_max(z, act, batch[r], pool, threadIdx.x & 63);
}

// -------- final: out = pool0 + pool1 + pool2 --------
extern "C" __global__ void k_out(const unsigned* __restrict__ pools,
                                 float* __restrict__ out) {
    int i = threadIdx.x;
    if (i < 128)
        out[i] = funmap(pools[i]) + funmap(pools[128 + i]) + funmap(pools[256 + i]);
}

extern "C" void kernel_launch(void* const* d_in, const int* in_sizes, int n_in,
                              void* d_out, int out_size, void* d_ws, size_t ws_size,
                              hipStream_t stream) {
    const float* x   = (const float*)d_in[0];
    const int* ei    = (const int*)d_in[1];
    const int* batch = (const int*)d_in[2];
    const float* W0  = (const float*)d_in[3];
    const float* b0  = (const float*)d_in[4];
    const float* g0  = (const float*)d_in[5];
    const float* be0 = (const float*)d_in[6];
    const float* Wl0 = (const float*)d_in[7];
    const float* bl0 = (const float*)d_in[8];
    const float* W1  = (const float*)d_in[9];
    const float* b1  = (const float*)d_in[10];
    const float* g1  = (const float*)d_in[11];
    const float* be1 = (const float*)d_in[12];
    const float* Wl1 = (const float*)d_in[13];
    const float* bl1 = (const float*)d_in[14];
    const float* W2  = (const float*)d_in[15];
    const float* b2  = (const float*)d_in[16];
    const float* g2  = (const float*)d_in[17];
    const float* be2 = (const float*)d_in[18];
    const float* Wl2 = (const float*)d_in[19];
    const float* bl2 = (const float*)d_in[20];

    const int* src = ei;
    const int* dst = ei + GE;

    char* ws = (char*)d_ws;
    double* stats0  = (double*)(ws + 0);
    double* stats1  = (double*)(ws + 256);
    double* stats2  = (double*)(ws + 512);
    float* sb0      = (float*)(ws + 640);
    float* sb1      = (float*)(ws + 768);
    float* sb2      = (float*)(ws + 896);
    unsigned* pools = (unsigned*)(ws + 960);
    float* pre      = (float*)(ws + 4096);
    float* hbuf     = (float*)(ws + 4096 + 6400000);
    float* agg      = (float*)(ws + 4096 + 12800000);

    float* out  = (float*)d_out;
    float* zsum = out + 128;
    float* hout = out + 128 + GN * GDT;

    int nb = (GN + 255) / 256;  // 391
    int eb = (GE + 255) / 256;  // 12500

    hipLaunchKernelGGL(k_init, dim3(1024), dim3(256), 0, stream,
                       (double*)ws, pools, agg);
    // layer 0
    hipLaunchKernelGGL(k_gemm0, dim3(nb), dim3(256), 0, stream, x, W0, b0, pre, stats0);
    hipLaunchKernelGGL(k_stats, dim3(1), dim3(32), 0, stream, stats0, g0, be0, sb0, 16);
    hipLaunchKernelGGL(k_apply0, dim3(nb), dim3(256), 0, stream,
                       pre, sb0, Wl0, bl0, batch, hbuf, zsum, pools);
    // layer 1
    hipLaunchKernelGGL(k_edge, dim3(eb), dim3(256), 0, stream, src, dst, hbuf, agg);
    hipLaunchKernelGGL(k_gemm1, dim3(nb), dim3(256), 0, stream, hbuf, agg, W1, b1, pre, stats1);
    hipLaunchKernelGGL(k_stats, dim3(1), dim3(32), 0, stream, stats1, g1, be1, sb1, 16);
    hipLaunchKernelGGL(k_apply1, dim3(nb), dim3(256), 0, stream,
                       pre, sb1, Wl1, bl1, batch, hbuf, zsum, pools + 128, agg);
    // layer 2
    hipLaunchKernelGGL(k_edge, dim3(eb), dim3(256), 0, stream, src, dst, hbuf, agg);
    hipLaunchKernelGGL(k_gemm2, dim3(nb), dim3(256), 0, stream, hbuf, agg, W2, b2, pre, stats2);
    hipLaunchKernelGGL(k_stats, dim3(1), dim3(32), 0, stream, stats2, g2, be2, sb2, 8);
    hipLaunchKernelGGL(k_apply2, dim3(nb), dim3(256), 0, stream,
                       pre, sb2, Wl2, bl2, batch, hout, zsum, pools + 256);
    hipLaunchKernelGGL(k_out, dim3(1), dim3(128), 0, stream, pools, out);
}

// Round 2
// 2015.658 us; speedup vs baseline: 3.1922x; 3.1922x over previous
//
#include <hip/hip_runtime.h>
#include <hip/hip_bf16.h>
#include <math.h>

#define GN 100000
#define GE 3200000
#define GNG 16
#define GF 512
#define GDT 8

#define NBK 391            // ceil(100000/256) dst buckets of 256 nodes
#define BCAP 10000         // bin capacity per bucket (mean 8192, sigma 90 -> +20 sigma)
#define ECH 12800          // edges per scatter block
#define EBLK 250           // 250*12800 = 3,200,000 = GE exactly

// ---------------- fast-path ws layout (bytes) ----------------
// 0        stats0 double[32] | 256 stats1 double[32] | 512 stats2 double[16]
// 640      sb0 f[32] | 768 sb1 f[32] | 896 sb2 f[16]
// 960      pools u32[384]
// 2560     gcursor u32[391]
// 8192     bins u32[391*10000]          (15,640,000 B)
// 15648256 pre  f[1.6M]  (6.4 MB)
// 22048256 hbuf f[1.6M]  (6.4 MB)
// 28448256 hsum f[1.6M]  (6.4 MB)      -> FAST_NEED = 34,848,256
#define FAST_NEED 34848256ull

__device__ __forceinline__ float geluf(float x) {
    return 0.5f * x * (1.0f + erff(x * 0.70710678118654752440f));
}
__device__ __forceinline__ unsigned fmap(float f) {
    unsigned u = __float_as_uint(f);
    return (u & 0x80000000u) ? ~u : (u | 0x80000000u);
}
__device__ __forceinline__ float funmap(unsigned u) {
    return __uint_as_float((u & 0x80000000u) ? (u ^ 0x80000000u) : ~u);
}

// -------- init: zero stats + cursors, init pools to mapped(-inf) --------
__global__ void k_init(double* __restrict__ stats, unsigned* __restrict__ pools,
                       unsigned* __restrict__ gcursor) {
    int i = threadIdx.x;
    if (i < 80) stats[i] = 0.0;
    if (i < 384) pools[i] = 0x007FFFFFu;  // fmap(-inf)
    if (i < NBK) gcursor[i] = 0u;
}

__global__ void k_zero(float* __restrict__ p, int n) {
    int i = blockIdx.x * 256 + threadIdx.x;
    if (i < n) p[i] = 0.0f;
}

// -------- wave-reduce per-column sum/sumsq into double stats --------
template <int C>
__device__ __forceinline__ void stats_reduce(const float* acc, double* stats, int lane) {
#pragma unroll
    for (int j = 0; j < C; ++j) {
        float s = acc[j];
        float q = acc[j] * acc[j];
#pragma unroll
        for (int o = 32; o > 0; o >>= 1) {
            s += __shfl_down(s, o);
            q += __shfl_down(q, o);
        }
        if (lane == 0) {
            atomicAdd(&stats[j], (double)s);
            atomicAdd(&stats[C + j], (double)q);
        }
    }
}

// -------- layer 0 GEMM: pre = x@W0 + b0, accumulate BN stats --------
extern "C" __global__ void __launch_bounds__(256)
k_gemm0(const float* __restrict__ x, const float* __restrict__ W,
        const float* __restrict__ b, float* __restrict__ pre,
        double* __restrict__ stats) {
    int r = blockIdx.x * 256 + threadIdx.x;
    bool act = r < GN;
    float acc[16];
#pragma unroll
    for (int j = 0; j < 16; ++j) acc[j] = act ? b[j] : 0.0f;
    if (act) {
        const float4* xr = (const float4*)(x + (size_t)r * GF);
#pragma unroll 8
        for (int kk = 0; kk < GF / 4; ++kk) {
            float4 xv = xr[kk];
            float xa[4] = {xv.x, xv.y, xv.z, xv.w};
#pragma unroll
            for (int d = 0; d < 4; ++d) {
                const float* wr = W + (kk * 4 + d) * 16;  // wave-uniform -> s_load
#pragma unroll
                for (int j = 0; j < 16; ++j) acc[j] = fmaf(xa[d], wr[j], acc[j]);
            }
        }
        float4* pr = (float4*)(pre + (size_t)r * 16);
        pr[0] = make_float4(acc[0], acc[1], acc[2], acc[3]);
        pr[1] = make_float4(acc[4], acc[5], acc[6], acc[7]);
        pr[2] = make_float4(acc[8], acc[9], acc[10], acc[11]);
        pr[3] = make_float4(acc[12], acc[13], acc[14], acc[15]);
    }
    stats_reduce<16>(acc, stats, threadIdx.x & 63);
}

// -------- finalize BN --------
extern "C" __global__ void k_stats(const double* __restrict__ stats,
                                   const float* __restrict__ g,
                                   const float* __restrict__ be,
                                   float* __restrict__ sb, int C) {
    int j = threadIdx.x;
    if (j >= C) return;
    double mu = stats[j] * (1.0 / GN);
    double var = stats[C + j] * (1.0 / GN) - mu * mu;
    float scale = g[j] / sqrtf((float)var + 1e-5f);
    sb[j] = scale;
    sb[C + j] = be[j] - (float)mu * scale;
}

// -------- pool helper: wave-max then atomicMax --------
__device__ __forceinline__ void pool_max(const float* z, bool act, int grp,
                                         unsigned* __restrict__ pool, int lane) {
    float mz[8];
#pragma unroll
    for (int jo = 0; jo < 8; ++jo) mz[jo] = act ? z[jo] : -INFINITY;
    int gl = __shfl(grp, 0);
    if (__all(grp == gl)) {
#pragma unroll
        for (int jo = 0; jo < 8; ++jo) {
            float m = mz[jo];
#pragma unroll
            for (int o = 32; o > 0; o >>= 1) m = fmaxf(m, __shfl_down(m, o));
            if (lane == 0) atomicMax(&pool[gl * 8 + jo], fmap(m));
        }
    } else {
        if (act) {
#pragma unroll
            for (int jo = 0; jo < 8; ++jo) atomicMax(&pool[grp * 8 + jo], fmap(mz[jo]));
        }
    }
}

// -------- layer 0 apply --------
extern "C" __global__ void __launch_bounds__(256)
k_apply0(const float* __restrict__ pre, const float* __restrict__ sb,
         const float* __restrict__ Wl, const float* __restrict__ bl,
         const int* __restrict__ batch, float* __restrict__ h,
         float* __restrict__ zsum, unsigned* __restrict__ pool) {
    int r0 = blockIdx.x * 256 + threadIdx.x;
    bool act = r0 < GN;
    int r = act ? r0 : (GN - 1);
    const float4* pr = (const float4*)(pre + (size_t)r * 16);
    float4 p0 = pr[0], p1 = pr[1], p2 = pr[2], p3 = pr[3];
    float pv[16] = {p0.x, p0.y, p0.z, p0.w, p1.x, p1.y, p1.z, p1.w,
                    p2.x, p2.y, p2.z, p2.w, p3.x, p3.y, p3.z, p3.w};
    float hv[16];
#pragma unroll
    for (int j = 0; j < 16; ++j) hv[j] = geluf(fmaf(pv[j], sb[j], sb[16 + j]));
    if (act) {
        float4* hr = (float4*)(h + (size_t)r * 16);
        hr[0] = make_float4(hv[0], hv[1], hv[2], hv[3]);
        hr[1] = make_float4(hv[4], hv[5], hv[6], hv[7]);
        hr[2] = make_float4(hv[8], hv[9], hv[10], hv[11]);
        hr[3] = make_float4(hv[12], hv[13], hv[14], hv[15]);
    }
    float z[8];
#pragma unroll
    for (int jo = 0; jo < 8; ++jo) {
        float a = bl[jo];
#pragma unroll
        for (int j = 0; j < 16; ++j) a = fmaf(hv[j], Wl[j * 8 + jo], a);
        z[jo] = geluf(a);
    }
    if (act) {
        float4* zr = (float4*)(zsum + (size_t)r * 8);
        zr[0] = make_float4(z[0], z[1], z[2], z[3]);
        zr[1] = make_float4(z[4], z[5], z[6], z[7]);
    }
    pool_max(z, act, batch[r], pool, threadIdx.x & 63);
}

// ======== FAST PATH: bucket counting-sort + LDS accumulation ========

// build bins: pack (src<<8)|dst_low sorted by bucket dst>>8
extern "C" __global__ void __launch_bounds__(256)
k_scatter(const int* __restrict__ src, const int* __restrict__ dst,
          unsigned* __restrict__ gcursor, unsigned* __restrict__ bins) {
    __shared__ unsigned hist[NBK];
    __shared__ unsigned gb[NBK];
    int t = threadIdx.x;
    for (int i = t; i < NBK; i += 256) hist[i] = 0u;
    __syncthreads();
    int e0 = blockIdx.x * ECH;
#pragma unroll 2
    for (int i = 0; i < ECH / 256; ++i) {
        int d = dst[e0 + i * 256 + t];
        atomicAdd(&hist[d >> 8], 1u);
    }
    __syncthreads();
    for (int i = t; i < NBK; i += 256) {
        unsigned c = hist[i];
        gb[i] = c ? atomicAdd(&gcursor[i], c) : 0u;
        hist[i] = 0u;
    }
    __syncthreads();
#pragma unroll 2
    for (int i = 0; i < ECH / 256; ++i) {
        int e = e0 + i * 256 + t;
        int d = dst[e];
        int s = src[e];
        int bk = d >> 8;
        unsigned r = atomicAdd(&hist[bk], 1u) + gb[bk];
        if (r < BCAP)
            bins[(unsigned)bk * BCAP + r] = ((unsigned)s << 8) | (unsigned)(d & 255);
    }
}

// per-bucket LDS accumulate: hsum = h + segment_sum(h[src])
extern "C" __global__ void __launch_bounds__(512)
k_agg(const float* __restrict__ h, const unsigned* __restrict__ gcursor,
      const unsigned* __restrict__ bins, float* __restrict__ hsum) {
    __shared__ float acc[16 * 257];  // col-major [j][dl], stride 257 -> bank (j+dl)%32
    int t = threadIdx.x;
    int b = blockIdx.x;
    for (int i = t; i < 16 * 257; i += 512) acc[i] = 0.0f;
    __syncthreads();
    unsigned cnt = gcursor[b];
    if (cnt > BCAP) cnt = BCAP;
    const unsigned* bp = bins + (unsigned)b * BCAP;
    for (unsigned i = t; i < cnt; i += 512) {
        unsigned p = bp[i];
        unsigned s = p >> 8;
        unsigned dl = p & 255u;
        const float4* hr = (const float4*)(h + (size_t)s * 16);
        float4 a0 = hr[0], a1 = hr[1], a2 = hr[2], a3 = hr[3];
        atomicAdd(&acc[0 * 257 + dl], a0.x);
        atomicAdd(&acc[1 * 257 + dl], a0.y);
        atomicAdd(&acc[2 * 257 + dl], a0.z);
        atomicAdd(&acc[3 * 257 + dl], a0.w);
        atomicAdd(&acc[4 * 257 + dl], a1.x);
        atomicAdd(&acc[5 * 257 + dl], a1.y);
        atomicAdd(&acc[6 * 257 + dl], a1.z);
        atomicAdd(&acc[7 * 257 + dl], a1.w);
        atomicAdd(&acc[8 * 257 + dl], a2.x);
        atomicAdd(&acc[9 * 257 + dl], a2.y);
        atomicAdd(&acc[10 * 257 + dl], a2.z);
        atomicAdd(&acc[11 * 257 + dl], a2.w);
        atomicAdd(&acc[12 * 257 + dl], a3.x);
        atomicAdd(&acc[13 * 257 + dl], a3.y);
        atomicAdd(&acc[14 * 257 + dl], a3.z);
        atomicAdd(&acc[15 * 257 + dl], a3.w);
    }
    __syncthreads();
    int base = b * 4096;  // 256 nodes * 16
    for (int w = t; w < 4096; w += 512) {
        int gw = base + w;
        if (gw < GN * 16) {
            int j = w & 15;
            int dl = (w >> 4) & 255;
            hsum[gw] = h[gw] + acc[j * 257 + dl];
        }
    }
}

// ======== fallback aggregation (round-1 proven): global atomics ========
extern "C" __global__ void __launch_bounds__(256)
k_edge(const int* __restrict__ src, const int* __restrict__ dst,
       const float* __restrict__ h, float* __restrict__ agg) {
    int e = blockIdx.x * 256 + threadIdx.x;
    if (e >= GE) return;
    int s = src[e], d = dst[e];
    const float4* hs = (const float4*)(h + (size_t)s * 16);
    float4 a = hs[0], b4 = hs[1], c = hs[2], w = hs[3];
    float* ad = agg + (size_t)d * 16;
    atomicAdd(ad + 0, a.x);  atomicAdd(ad + 1, a.y);
    atomicAdd(ad + 2, a.z);  atomicAdd(ad + 3, a.w);
    atomicAdd(ad + 4, b4.x); atomicAdd(ad + 5, b4.y);
    atomicAdd(ad + 6, b4.z); atomicAdd(ad + 7, b4.w);
    atomicAdd(ad + 8, c.x);  atomicAdd(ad + 9, c.y);
    atomicAdd(ad + 10, c.z); atomicAdd(ad + 11, c.w);
    atomicAdd(ad + 12, w.x); atomicAdd(ad + 13, w.y);
    atomicAdd(ad + 14, w.z); atomicAdd(ad + 15, w.w);
}

extern "C" __global__ void k_hadd(float* __restrict__ h, const float* __restrict__ agg) {
    int i = blockIdx.x * 256 + threadIdx.x;
    if (i < GN * 16) h[i] += agg[i];
}

// -------- layer 1 GEMM: pre = hsum@W1 + b1, stats --------
extern "C" __global__ void __launch_bounds__(256)
k_gemm1(const float* __restrict__ hsum, const float* __restrict__ W,
        const float* __restrict__ b, float* __restrict__ pre,
        double* __restrict__ stats) {
    int r = blockIdx.x * 256 + threadIdx.x;
    bool act = r < GN;
    float acc[16];
#pragma unroll
    for (int j = 0; j < 16; ++j) acc[j] = act ? b[j] : 0.0f;
    if (act) {
        const float4* hr = (const float4*)(hsum + (size_t)r * 16);
        float t[16];
#pragma unroll
        for (int c = 0; c < 4; ++c) {
            float4 u = hr[c];
            t[c * 4 + 0] = u.x; t[c * 4 + 1] = u.y;
            t[c * 4 + 2] = u.z; t[c * 4 + 3] = u.w;
        }
#pragma unroll
        for (int k = 0; k < 16; ++k)
#pragma unroll
            for (int j = 0; j < 16; ++j) acc[j] = fmaf(t[k], W[k * 16 + j], acc[j]);
        float4* pr = (float4*)(pre + (size_t)r * 16);
        pr[0] = make_float4(acc[0], acc[1], acc[2], acc[3]);
        pr[1] = make_float4(acc[4], acc[5], acc[6], acc[7]);
        pr[2] = make_float4(acc[8], acc[9], acc[10], acc[11]);
        pr[3] = make_float4(acc[12], acc[13], acc[14], acc[15]);
    }
    stats_reduce<16>(acc, stats, threadIdx.x & 63);
}

// -------- layer 1 apply --------
extern "C" __global__ void __launch_bounds__(256)
k_apply1(const float* __restrict__ pre, const float* __restrict__ sb,
         const float* __restrict__ Wl, const float* __restrict__ bl,
         const int* __restrict__ batch, float* __restrict__ h,
         float* __restrict__ zsum, unsigned* __restrict__ pool) {
    int r0 = blockIdx.x * 256 + threadIdx.x;
    bool act = r0 < GN;
    int r = act ? r0 : (GN - 1);
    const float4* pr = (const float4*)(pre + (size_t)r * 16);
    float4 p0 = pr[0], p1 = pr[1], p2 = pr[2], p3 = pr[3];
    float pv[16] = {p0.x, p0.y, p0.z, p0.w, p1.x, p1.y, p1.z, p1.w,
                    p2.x, p2.y, p2.z, p2.w, p3.x, p3.y, p3.z, p3.w};
    float hv[16];
#pragma unroll
    for (int j = 0; j < 16; ++j) hv[j] = fmaf(pv[j], sb[j], sb[16 + j]);
    if (act) {
        float4* hr = (float4*)(h + (size_t)r * 16);
        hr[0] = make_float4(hv[0], hv[1], hv[2], hv[3]);
        hr[1] = make_float4(hv[4], hv[5], hv[6], hv[7]);
        hr[2] = make_float4(hv[8], hv[9], hv[10], hv[11]);
        hr[3] = make_float4(hv[12], hv[13], hv[14], hv[15]);
    }
    float z[8];
#pragma unroll
    for (int jo = 0; jo < 8; ++jo) {
        float a = bl[jo];
#pragma unroll
        for (int j = 0; j < 16; ++j) a = fmaf(hv[j], Wl[j * 8 + jo], a);
        z[jo] = a;
    }
    if (act) {
        float4* zr = (float4*)(zsum + (size_t)r * 8);
        float4 z0 = zr[0], z1 = zr[1];
        zr[0] = make_float4(z0.x + z[0], z0.y + z[1], z0.z + z[2], z0.w + z[3]);
        zr[1] = make_float4(z1.x + z[4], z1.y + z[5], z1.z + z[6], z1.w + z[7]);
    }
    pool_max(z, act, batch[r], pool, threadIdx.x & 63);
}

// -------- layer 2 GEMM: pre8 = hsum@W2 + b2, stats (C=8) --------
extern "C" __global__ void __launch_bounds__(256)
k_gemm2(const float* __restrict__ hsum, const float* __restrict__ W,
        const float* __restrict__ b, float* __restrict__ pre,
        double* __restrict__ stats) {
    int r = blockIdx.x * 256 + threadIdx.x;
    bool act = r < GN;
    float acc[8];
#pragma unroll
    for (int j = 0; j < 8; ++j) acc[j] = act ? b[j] : 0.0f;
    if (act) {
        const float4* hr = (const float4*)(hsum + (size_t)r * 16);
        float t[16];
#pragma unroll
        for (int c = 0; c < 4; ++c) {
            float4 u = hr[c];
            t[c * 4 + 0] = u.x; t[c * 4 + 1] = u.y;
            t[c * 4 + 2] = u.z; t[c * 4 + 3] = u.w;
        }
#pragma unroll
        for (int k = 0; k < 16; ++k)
#pragma unroll
            for (int j = 0; j < 8; ++j) acc[j] = fmaf(t[k], W[k * 8 + j], acc[j]);
        float4* pr = (float4*)(pre + (size_t)r * 8);
        pr[0] = make_float4(acc[0], acc[1], acc[2], acc[3]);
        pr[1] = make_float4(acc[4], acc[5], acc[6], acc[7]);
    }
    stats_reduce<8>(acc, stats, threadIdx.x & 63);
}

// -------- layer 2 apply --------
extern "C" __global__ void __launch_bounds__(256)
k_apply2(const float* __restrict__ pre, const float* __restrict__ sb,
         const float* __restrict__ Wl, const float* __restrict__ bl,
         const int* __restrict__ batch, float* __restrict__ hout,
         float* __restrict__ zsum, unsigned* __restrict__ pool) {
    int r0 = blockIdx.x * 256 + threadIdx.x;
    bool act = r0 < GN;
    int r = act ? r0 : (GN - 1);
    const float4* pr = (const float4*)(pre + (size_t)r * 8);
    float4 p0 = pr[0], p1 = pr[1];
    float pv[8] = {p0.x, p0.y, p0.z, p0.w, p1.x, p1.y, p1.z, p1.w};
    float hv[8];
#pragma unroll
    for (int j = 0; j < 8; ++j) hv[j] = fmaf(pv[j], sb[j], sb[8 + j]);
    if (act) {
        float4* hr = (float4*)(hout + (size_t)r * 8);
        hr[0] = make_float4(hv[0], hv[1], hv[2], hv[3]);
        hr[1] = make_float4(hv[4], hv[5], hv[6], hv[7]);
    }
    float z[8];
#pragma unroll
    for (int jo = 0; jo < 8; ++jo) {
        float a = bl[jo];
#pragma unroll
        for (int j = 0; j < 8; ++j) a = fmaf(hv[j], Wl[j * 8 + jo], a);
        z[jo] = a;
    }
    if (act) {
        float4* zr = (float4*)(zsum + (size_t)r * 8);
        float4 z0 = zr[0], z1 = zr[1];
        zr[0] = make_float4(z0.x + z[0], z0.y + z[1], z0.z + z[2], z0.w + z[3]);
        zr[1] = make_float4(z1.x + z[4], z1.y + z[5], z1.z + z[6], z1.w + z[7]);
    }
    pool_max(z, act, batch[r], pool, threadIdx.x & 63);
}

// -------- final: out = pool0 + pool1 + pool2 --------
extern "C" __global__ void k_out(const unsigned* __restrict__ pools,
                                 float* __restrict__ out) {
    int i = threadIdx.x;
    if (i < 128)
        out[i] = funmap(pools[i]) + funmap(pools[128 + i]) + funmap(pools[256 + i]);
}

extern "C" void kernel_launch(void* const* d_in, const int* in_sizes, int n_in,
                              void* d_out, int out_size, void* d_ws, size_t ws_size,
                              hipStream_t stream) {
    const float* x   = (const float*)d_in[0];
    const int* ei    = (const int*)d_in[1];
    const int* batch = (const int*)d_in[2];
    const float* W0  = (const float*)d_in[3];
    const float* b0  = (const float*)d_in[4];
    const float* g0  = (const float*)d_in[5];
    const float* be0 = (const float*)d_in[6];
    const float* Wl0 = (const float*)d_in[7];
    const float* bl0 = (const float*)d_in[8];
    const float* W1  = (const float*)d_in[9];
    const float* b1  = (const float*)d_in[10];
    const float* g1  = (const float*)d_in[11];
    const float* be1 = (const float*)d_in[12];
    const float* Wl1 = (const float*)d_in[13];
    const float* bl1 = (const float*)d_in[14];
    const float* W2  = (const float*)d_in[15];
    const float* b2  = (const float*)d_in[16];
    const float* g2  = (const float*)d_in[17];
    const float* be2 = (const float*)d_in[18];
    const float* Wl2 = (const float*)d_in[19];
    const float* bl2 = (const float*)d_in[20];

    const int* src = ei;
    const int* dst = ei + GE;

    char* ws = (char*)d_ws;
    double* stats0  = (double*)(ws + 0);
    double* stats1  = (double*)(ws + 256);
    double* stats2  = (double*)(ws + 512);
    float* sb0      = (float*)(ws + 640);
    float* sb1      = (float*)(ws + 768);
    float* sb2      = (float*)(ws + 896);
    unsigned* pools = (unsigned*)(ws + 960);

    float* out  = (float*)d_out;
    float* zsum = out + 128;
    float* hout = out + 128 + GN * GDT;

    int nb = (GN + 255) / 256;  // 391
    bool fast = ws_size >= FAST_NEED;

    if (fast) {
        unsigned* gcursor = (unsigned*)(ws + 2560);
        unsigned* bins    = (unsigned*)(ws + 8192);
        float* pre  = (float*)(ws + 15648256);
        float* hbuf = (float*)(ws + 22048256);
        float* hsum = (float*)(ws + 28448256);

        hipLaunchKernelGGL(k_init, dim3(1), dim3(512), 0, stream, stats0, pools, gcursor);
        // bins are layer-independent: build once, reuse for both aggregations
        hipLaunchKernelGGL(k_scatter, dim3(EBLK), dim3(256), 0, stream, src, dst, gcursor, bins);
        // layer 0
        hipLaunchKernelGGL(k_gemm0, dim3(nb), dim3(256), 0, stream, x, W0, b0, pre, stats0);
        hipLaunchKernelGGL(k_stats, dim3(1), dim3(32), 0, stream, stats0, g0, be0, sb0, 16);
        hipLaunchKernelGGL(k_apply0, dim3(nb), dim3(256), 0, stream,
                           pre, sb0, Wl0, bl0, batch, hbuf, zsum, pools);
        // layer 1
        hipLaunchKernelGGL(k_agg, dim3(NBK), dim3(512), 0, stream, hbuf, gcursor, bins, hsum);
        hipLaunchKernelGGL(k_gemm1, dim3(nb), dim3(256), 0, stream, hsum, W1, b1, pre, stats1);
        hipLaunchKernelGGL(k_stats, dim3(1), dim3(32), 0, stream, stats1, g1, be1, sb1, 16);
        hipLaunchKernelGGL(k_apply1, dim3(nb), dim3(256), 0, stream,
                           pre, sb1, Wl1, bl1, batch, hbuf, zsum, pools + 128);
        // layer 2
        hipLaunchKernelGGL(k_agg, dim3(NBK), dim3(512), 0, stream, hbuf, gcursor, bins, hsum);
        hipLaunchKernelGGL(k_gemm2, dim3(nb), dim3(256), 0, stream, hsum, W2, b2, pre, stats2);
        hipLaunchKernelGGL(k_stats, dim3(1), dim3(32), 0, stream, stats2, g2, be2, sb2, 8);
        hipLaunchKernelGGL(k_apply2, dim3(nb), dim3(256), 0, stream,
                           pre, sb2, Wl2, bl2, batch, hout, zsum, pools + 256);
        hipLaunchKernelGGL(k_out, dim3(1), dim3(128), 0, stream, pools, out);
    } else {
        // round-1 proven fallback (global-atomic aggregation), ~19.2 MB ws
        float* pre  = (float*)(ws + 4096);
        float* hbuf = (float*)(ws + 4096 + 6400000);
        float* agg  = (float*)(ws + 4096 + 12800000);
        int eb = (GE + 255) / 256;

        hipLaunchKernelGGL(k_init, dim3(1), dim3(512), 0, stream, stats0, pools, (unsigned*)pre);
        hipLaunchKernelGGL(k_gemm0, dim3(nb), dim3(256), 0, stream, x, W0, b0, pre, stats0);
        hipLaunchKernelGGL(k_stats, dim3(1), dim3(32), 0, stream, stats0, g0, be0, sb0, 16);
        hipLaunchKernelGGL(k_apply0, dim3(nb), dim3(256), 0, stream,
                           pre, sb0, Wl0, bl0, batch, hbuf, zsum, pools);
        hipLaunchKernelGGL(k_zero, dim3(6250), dim3(256), 0, stream, agg, GN * 16);
        hipLaunchKernelGGL(k_edge, dim3(eb), dim3(256), 0, stream, src, dst, hbuf, agg);
        hipLaunchKernelGGL(k_hadd, dim3(6250), dim3(256), 0, stream, hbuf, agg);
        hipLaunchKernelGGL(k_gemm1, dim3(nb), dim3(256), 0, stream, hbuf, W1, b1, pre, stats1);
        hipLaunchKernelGGL(k_stats, dim3(1), dim3(32), 0, stream, stats1, g1, be1, sb1, 16);
        hipLaunchKernelGGL(k_apply1, dim3(nb), dim3(256), 0, stream,
                           pre, sb1, Wl1, bl1, batch, hbuf, zsum, pools + 128);
        hipLaunchKernelGGL(k_zero, dim3(6250), dim3(256), 0, stream, agg, GN * 16);
        hipLaunchKernelGGL(k_edge, dim3(eb), dim3(256), 0, stream, src, dst, hbuf, agg);
        hipLaunchKernelGGL(k_hadd, dim3(6250), dim3(256), 0, stream, hbuf, agg);
        hipLaunchKernelGGL(k_gemm2, dim3(nb), dim3(256), 0, stream, hbuf, W2, b2, pre, stats2);
        hipLaunchKernelGGL(k_stats, dim3(1), dim3(32), 0, stream, stats2, g2, be2, sb2, 8);
        hipLaunchKernelGGL(k_apply2, dim3(nb), dim3(256), 0, stream,
                           pre, sb2, Wl2, bl2, batch, hout, zsum, pools + 256);
        hipLaunchKernelGGL(k_out, dim3(1), dim3(128), 0, stream, pools, out);
    }
}

// Round 3
// 1300.503 us; speedup vs baseline: 4.9477x; 1.5499x over previous
//
#include <hip/hip_runtime.h>
#include <hip/hip_bf16.h>
#include <math.h>

#define GN 100000
#define GE 3200000
#define GNG 16
#define GF 512
#define GDT 8

#define NBK 391            // ceil(100000/256) dst buckets of 256 nodes
#define BCAP 10000         // bin capacity per bucket (mean 8192, sigma 90 -> +20 sigma)
#define ECH 12800          // edges per scatter block
#define EBLK 250           // 250*12800 = 3,200,000 = GE exactly

// ---------------- fast-path ws layout (bytes) ----------------
// 0        stats0 double[32] | 256 stats1 double[32] | 512 stats2 double[16]
// 640      sb0 f[32] | 768 sb1 f[32] | 896 sb2 f[16]
// 960      pools u32[384]
// 2560     gcursor u32[391]
// 8192     bins u32[391*10000]          (15,640,000 B)
// 15648256 pre  f[1.6M]  (6.4 MB)
// 22048256 hbuf f[1.6M]  (6.4 MB)
// 28448256 (spare, was hsum)            -> FAST_NEED = 34,848,256
#define FAST_NEED 34848256ull

__device__ __forceinline__ float geluf(float x) {
    return 0.5f * x * (1.0f + erff(x * 0.70710678118654752440f));
}
__device__ __forceinline__ unsigned fmap(float f) {
    unsigned u = __float_as_uint(f);
    return (u & 0x80000000u) ? ~u : (u | 0x80000000u);
}
__device__ __forceinline__ float funmap(unsigned u) {
    return __uint_as_float((u & 0x80000000u) ? (u ^ 0x80000000u) : ~u);
}

// -------- init: zero stats + cursors, init pools to mapped(-inf) --------
__global__ void k_init(double* __restrict__ stats, unsigned* __restrict__ pools,
                       unsigned* __restrict__ gcursor) {
    int i = threadIdx.x;
    if (i < 80) stats[i] = 0.0;
    if (i < 384) pools[i] = 0x007FFFFFu;  // fmap(-inf)
    if (i < NBK) gcursor[i] = 0u;
}

__global__ void k_zero(float* __restrict__ p, int n) {
    int i = blockIdx.x * 256 + threadIdx.x;
    if (i < n) p[i] = 0.0f;
}

// -------- wave-reduce per-column sum/sumsq into fp32 LDS block funnel --------
template <int C>
__device__ __forceinline__ void stats_funnel(const float* acc, float* bstat, int lane) {
#pragma unroll
    for (int j = 0; j < C; ++j) {
        float s = acc[j];
        float q = acc[j] * acc[j];
#pragma unroll
        for (int o = 32; o > 0; o >>= 1) {
            s += __shfl_down(s, o);
            q += __shfl_down(q, o);
        }
        if (lane == 0) {
            atomicAdd(&bstat[j], s);
            atomicAdd(&bstat[C + j], q);
        }
    }
}

// -------- legacy global-atomic stats (fallback path only) --------
template <int C>
__device__ __forceinline__ void stats_reduce(const float* acc, double* stats, int lane) {
#pragma unroll
    for (int j = 0; j < C; ++j) {
        float s = acc[j];
        float q = acc[j] * acc[j];
#pragma unroll
        for (int o = 32; o > 0; o >>= 1) {
            s += __shfl_down(s, o);
            q += __shfl_down(q, o);
        }
        if (lane == 0) {
            atomicAdd(&stats[j], (double)s);
            atomicAdd(&stats[C + j], (double)q);
        }
    }
}

// -------- layer 0 GEMM v3: W staged in LDS (kills scalar-cache stalls) --------
// pre = x@W0 + b0, BN stats via LDS funnel.
extern "C" __global__ void __launch_bounds__(256)
k_gemm0(const float* __restrict__ x, const float* __restrict__ W,
        const float* __restrict__ b, float* __restrict__ pre,
        double* __restrict__ stats) {
    __shared__ float wlds[GF * 16];   // 32 KB: full W0
    __shared__ float bstat[32];
    int t = threadIdx.x;
    {   // stage W coalesced: 2048 float4 / 256 threads = 8 each
        const float4* Wv = (const float4*)W;
        float4* Lv = (float4*)wlds;
#pragma unroll
        for (int i = 0; i < 8; ++i) Lv[t + 256 * i] = Wv[t + 256 * i];
    }
    if (t < 32) bstat[t] = 0.0f;
    __syncthreads();

    int r = blockIdx.x * 256 + t;
    bool act = r < GN;
    float acc[16];
#pragma unroll
    for (int j = 0; j < 16; ++j) acc[j] = 0.0f;
    if (act) {
        const float4* xr = (const float4*)(x + (size_t)r * GF);
#pragma unroll 8
        for (int kk = 0; kk < GF / 4; ++kk) {
            float4 xv = xr[kk];
            float xa[4] = {xv.x, xv.y, xv.z, xv.w};
#pragma unroll
            for (int d = 0; d < 4; ++d) {
                const float* wr = &wlds[(kk * 4 + d) * 16];  // wave-uniform -> LDS broadcast
#pragma unroll
                for (int j = 0; j < 16; ++j) acc[j] = fmaf(xa[d], wr[j], acc[j]);
            }
        }
#pragma unroll
        for (int j = 0; j < 16; ++j) acc[j] += b[j];
        float4* pr = (float4*)(pre + (size_t)r * 16);
        pr[0] = make_float4(acc[0], acc[1], acc[2], acc[3]);
        pr[1] = make_float4(acc[4], acc[5], acc[6], acc[7]);
        pr[2] = make_float4(acc[8], acc[9], acc[10], acc[11]);
        pr[3] = make_float4(acc[12], acc[13], acc[14], acc[15]);
    }
    // inactive rows contribute zeros
    stats_funnel<16>(acc, bstat, t & 63);
    __syncthreads();
    if (t < 32) atomicAdd(&stats[t], (double)bstat[t]);
}

// -------- finalize BN --------
extern "C" __global__ void k_stats(const double* __restrict__ stats,
                                   const float* __restrict__ g,
                                   const float* __restrict__ be,
                                   float* __restrict__ sb, int C) {
    int j = threadIdx.x;
    if (j >= C) return;
    double mu = stats[j] * (1.0 / GN);
    double var = stats[C + j] * (1.0 / GN) - mu * mu;
    float scale = g[j] / sqrtf((float)var + 1e-5f);
    sb[j] = scale;
    sb[C + j] = be[j] - (float)mu * scale;
}

// -------- pool helper: wave-max then atomicMax --------
__device__ __forceinline__ void pool_max(const float* z, bool act, int grp,
                                         unsigned* __restrict__ pool, int lane) {
    float mz[8];
#pragma unroll
    for (int jo = 0; jo < 8; ++jo) mz[jo] = act ? z[jo] : -INFINITY;
    int gl = __shfl(grp, 0);
    if (__all(grp == gl)) {
#pragma unroll
        for (int jo = 0; jo < 8; ++jo) {
            float m = mz[jo];
#pragma unroll
            for (int o = 32; o > 0; o >>= 1) m = fmaxf(m, __shfl_down(m, o));
            if (lane == 0) atomicMax(&pool[gl * 8 + jo], fmap(m));
        }
    } else {
        if (act) {
#pragma unroll
            for (int jo = 0; jo < 8; ++jo) atomicMax(&pool[grp * 8 + jo], fmap(mz[jo]));
        }
    }
}

// -------- layer 0 apply --------
extern "C" __global__ void __launch_bounds__(256)
k_apply0(const float* __restrict__ pre, const float* __restrict__ sb,
         const float* __restrict__ Wl, const float* __restrict__ bl,
         const int* __restrict__ batch, float* __restrict__ h,
         float* __restrict__ zsum, unsigned* __restrict__ pool) {
    int r0 = blockIdx.x * 256 + threadIdx.x;
    bool act = r0 < GN;
    int r = act ? r0 : (GN - 1);
    const float4* pr = (const float4*)(pre + (size_t)r * 16);
    float4 p0 = pr[0], p1 = pr[1], p2 = pr[2], p3 = pr[3];
    float pv[16] = {p0.x, p0.y, p0.z, p0.w, p1.x, p1.y, p1.z, p1.w,
                    p2.x, p2.y, p2.z, p2.w, p3.x, p3.y, p3.z, p3.w};
    float hv[16];
#pragma unroll
    for (int j = 0; j < 16; ++j) hv[j] = geluf(fmaf(pv[j], sb[j], sb[16 + j]));
    if (act) {
        float4* hr = (float4*)(h + (size_t)r * 16);
        hr[0] = make_float4(hv[0], hv[1], hv[2], hv[3]);
        hr[1] = make_float4(hv[4], hv[5], hv[6], hv[7]);
        hr[2] = make_float4(hv[8], hv[9], hv[10], hv[11]);
        hr[3] = make_float4(hv[12], hv[13], hv[14], hv[15]);
    }
    float z[8];
#pragma unroll
    for (int jo = 0; jo < 8; ++jo) {
        float a = bl[jo];
#pragma unroll
        for (int j = 0; j < 16; ++j) a = fmaf(hv[j], Wl[j * 8 + jo], a);
        z[jo] = geluf(a);
    }
    if (act) {
        float4* zr = (float4*)(zsum + (size_t)r * 8);
        zr[0] = make_float4(z[0], z[1], z[2], z[3]);
        zr[1] = make_float4(z[4], z[5], z[6], z[7]);
    }
    pool_max(z, act, batch[r], pool, threadIdx.x & 63);
}

// ======== FAST PATH: bucket counting-sort, then fused agg+GEMM ========

// build bins: pack (src<<8)|dst_low sorted by bucket dst>>8
extern "C" __global__ void __launch_bounds__(256)
k_scatter(const int* __restrict__ src, const int* __restrict__ dst,
          unsigned* __restrict__ gcursor, unsigned* __restrict__ bins) {
    __shared__ unsigned hist[NBK];
    __shared__ unsigned gb[NBK];
    int t = threadIdx.x;
    for (int i = t; i < NBK; i += 256) hist[i] = 0u;
    __syncthreads();
    int e0 = blockIdx.x * ECH;
#pragma unroll 2
    for (int i = 0; i < ECH / 256; ++i) {
        int d = dst[e0 + i * 256 + t];
        atomicAdd(&hist[d >> 8], 1u);
    }
    __syncthreads();
    for (int i = t; i < NBK; i += 256) {
        unsigned c = hist[i];
        gb[i] = c ? atomicAdd(&gcursor[i], c) : 0u;
        hist[i] = 0u;
    }
    __syncthreads();
#pragma unroll 2
    for (int i = 0; i < ECH / 256; ++i) {
        int e = e0 + i * 256 + t;
        int d = dst[e];
        int s = src[e];
        int bk = d >> 8;
        unsigned r = atomicAdd(&hist[bk], 1u) + gb[bk];
        if (r < BCAP)
            bins[(unsigned)bk * BCAP + r] = ((unsigned)s << 8) | (unsigned)(d & 255);
    }
}

// fused: hsum(LDS) = h + segment_sum(h[src]); pre = hsum@W + b; BN stats.
// 4 lanes per edge (16B/lane gather -> one 64B line per edge-group).
template <int CO>
__global__ void __launch_bounds__(512)
k_agggemm(const float* __restrict__ h, const unsigned* __restrict__ gcursor,
          const unsigned* __restrict__ bins, const float* __restrict__ W,
          const float* __restrict__ b, float* __restrict__ pre,
          double* __restrict__ stats) {
    __shared__ float acc[16 * 257];  // col-major [j][dl], stride 257
    __shared__ float bstat[2 * CO];
    int t = threadIdx.x;
    int bk = blockIdx.x;
    for (int i = t; i < 16 * 257; i += 512) acc[i] = 0.0f;
    if (t < 2 * CO) bstat[t] = 0.0f;
    __syncthreads();

    unsigned cnt = gcursor[bk];
    if (cnt > BCAP) cnt = BCAP;
    const unsigned* bp = bins + (size_t)bk * BCAP;
    int c = t & 3;
    for (unsigned i = (unsigned)(t >> 2); i < cnt; i += 128) {
        unsigned p = bp[i];           // 4 lanes same addr -> broadcast
        unsigned s = p >> 8;
        unsigned dl = p & 255u;
        float4 v = *(const float4*)(h + (size_t)s * 16 + c * 4);
        atomicAdd(&acc[(4 * c + 0) * 257 + dl], v.x);
        atomicAdd(&acc[(4 * c + 1) * 257 + dl], v.y);
        atomicAdd(&acc[(4 * c + 2) * 257 + dl], v.z);
        atomicAdd(&acc[(4 * c + 3) * 257 + dl], v.w);
    }
    __syncthreads();

    if (t < 256) {
        int gn = bk * 256 + t;
        bool act = gn < GN;
        float hv[16];
        float z[CO];
        if (act) {
            const float4* hr = (const float4*)(h + (size_t)gn * 16);
#pragma unroll
            for (int cq = 0; cq < 4; ++cq) {
                float4 u = hr[cq];
                hv[4 * cq + 0] = u.x + acc[(4 * cq + 0) * 257 + t];
                hv[4 * cq + 1] = u.y + acc[(4 * cq + 1) * 257 + t];
                hv[4 * cq + 2] = u.z + acc[(4 * cq + 2) * 257 + t];
                hv[4 * cq + 3] = u.w + acc[(4 * cq + 3) * 257 + t];
            }
        } else {
#pragma unroll
            for (int j = 0; j < 16; ++j) hv[j] = 0.0f;
        }
#pragma unroll
        for (int jo = 0; jo < CO; ++jo) {
            float a = act ? b[jo] : 0.0f;
#pragma unroll
            for (int j = 0; j < 16; ++j) a = fmaf(hv[j], W[j * CO + jo], a);
            z[jo] = a;
        }
        if (act) {
            float4* prow = (float4*)(pre + (size_t)gn * CO);
#pragma unroll
            for (int q = 0; q < CO / 4; ++q)
                prow[q] = make_float4(z[4 * q + 0], z[4 * q + 1], z[4 * q + 2], z[4 * q + 3]);
        }
        stats_funnel<CO>(z, bstat, t & 63);
    }
    __syncthreads();
    if (t < 2 * CO) atomicAdd(&stats[t], (double)bstat[t]);
}

// ======== fallback aggregation (round-1 proven): global atomics ========
extern "C" __global__ void __launch_bounds__(256)
k_edge(const int* __restrict__ src, const int* __restrict__ dst,
       const float* __restrict__ h, float* __restrict__ agg) {
    int e = blockIdx.x * 256 + threadIdx.x;
    if (e >= GE) return;
    int s = src[e], d = dst[e];
    const float4* hs = (const float4*)(h + (size_t)s * 16);
    float4 a = hs[0], b4 = hs[1], c = hs[2], w = hs[3];
    float* ad = agg + (size_t)d * 16;
    atomicAdd(ad + 0, a.x);  atomicAdd(ad + 1, a.y);
    atomicAdd(ad + 2, a.z);  atomicAdd(ad + 3, a.w);
    atomicAdd(ad + 4, b4.x); atomicAdd(ad + 5, b4.y);
    atomicAdd(ad + 6, b4.z); atomicAdd(ad + 7, b4.w);
    atomicAdd(ad + 8, c.x);  atomicAdd(ad + 9, c.y);
    atomicAdd(ad + 10, c.z); atomicAdd(ad + 11, c.w);
    atomicAdd(ad + 12, w.x); atomicAdd(ad + 13, w.y);
    atomicAdd(ad + 14, w.z); atomicAdd(ad + 15, w.w);
}

extern "C" __global__ void k_hadd(float* __restrict__ h, const float* __restrict__ agg) {
    int i = blockIdx.x * 256 + threadIdx.x;
    if (i < GN * 16) h[i] += agg[i];
}

// -------- fallback layer-1/2 GEMMs (hsum precombined into h via k_hadd) --------
extern "C" __global__ void __launch_bounds__(256)
k_gemm1(const float* __restrict__ hsum, const float* __restrict__ W,
        const float* __restrict__ b, float* __restrict__ pre,
        double* __restrict__ stats) {
    int r = blockIdx.x * 256 + threadIdx.x;
    bool act = r < GN;
    float acc[16];
#pragma unroll
    for (int j = 0; j < 16; ++j) acc[j] = act ? b[j] : 0.0f;
    if (act) {
        const float4* hr = (const float4*)(hsum + (size_t)r * 16);
        float tv[16];
#pragma unroll
        for (int cq = 0; cq < 4; ++cq) {
            float4 u = hr[cq];
            tv[cq * 4 + 0] = u.x; tv[cq * 4 + 1] = u.y;
            tv[cq * 4 + 2] = u.z; tv[cq * 4 + 3] = u.w;
        }
#pragma unroll
        for (int k = 0; k < 16; ++k)
#pragma unroll
            for (int j = 0; j < 16; ++j) acc[j] = fmaf(tv[k], W[k * 16 + j], acc[j]);
        float4* pr = (float4*)(pre + (size_t)r * 16);
        pr[0] = make_float4(acc[0], acc[1], acc[2], acc[3]);
        pr[1] = make_float4(acc[4], acc[5], acc[6], acc[7]);
        pr[2] = make_float4(acc[8], acc[9], acc[10], acc[11]);
        pr[3] = make_float4(acc[12], acc[13], acc[14], acc[15]);
    }
    stats_reduce<16>(acc, stats, threadIdx.x & 63);
}

extern "C" __global__ void __launch_bounds__(256)
k_gemm2(const float* __restrict__ hsum, const float* __restrict__ W,
        const float* __restrict__ b, float* __restrict__ pre,
        double* __restrict__ stats) {
    int r = blockIdx.x * 256 + threadIdx.x;
    bool act = r < GN;
    float acc[8];
#pragma unroll
    for (int j = 0; j < 8; ++j) acc[j] = act ? b[j] : 0.0f;
    if (act) {
        const float4* hr = (const float4*)(hsum + (size_t)r * 16);
        float tv[16];
#pragma unroll
        for (int cq = 0; cq < 4; ++cq) {
            float4 u = hr[cq];
            tv[cq * 4 + 0] = u.x; tv[cq * 4 + 1] = u.y;
            tv[cq * 4 + 2] = u.z; tv[cq * 4 + 3] = u.w;
        }
#pragma unroll
        for (int k = 0; k < 16; ++k)
#pragma unroll
            for (int j = 0; j < 8; ++j) acc[j] = fmaf(tv[k], W[k * 8 + j], acc[j]);
        float4* pr = (float4*)(pre + (size_t)r * 8);
        pr[0] = make_float4(acc[0], acc[1], acc[2], acc[3]);
        pr[1] = make_float4(acc[4], acc[5], acc[6], acc[7]);
    }
    stats_reduce<8>(acc, stats, threadIdx.x & 63);
}

// -------- layer 1 apply --------
extern "C" __global__ void __launch_bounds__(256)
k_apply1(const float* __restrict__ pre, const float* __restrict__ sb,
         const float* __restrict__ Wl, const float* __restrict__ bl,
         const int* __restrict__ batch, float* __restrict__ h,
         float* __restrict__ zsum, unsigned* __restrict__ pool) {
    int r0 = blockIdx.x * 256 + threadIdx.x;
    bool act = r0 < GN;
    int r = act ? r0 : (GN - 1);
    const float4* pr = (const float4*)(pre + (size_t)r * 16);
    float4 p0 = pr[0], p1 = pr[1], p2 = pr[2], p3 = pr[3];
    float pv[16] = {p0.x, p0.y, p0.z, p0.w, p1.x, p1.y, p1.z, p1.w,
                    p2.x, p2.y, p2.z, p2.w, p3.x, p3.y, p3.z, p3.w};
    float hv[16];
#pragma unroll
    for (int j = 0; j < 16; ++j) hv[j] = fmaf(pv[j], sb[j], sb[16 + j]);
    if (act) {
        float4* hr = (float4*)(h + (size_t)r * 16);
        hr[0] = make_float4(hv[0], hv[1], hv[2], hv[3]);
        hr[1] = make_float4(hv[4], hv[5], hv[6], hv[7]);
        hr[2] = make_float4(hv[8], hv[9], hv[10], hv[11]);
        hr[3] = make_float4(hv[12], hv[13], hv[14], hv[15]);
    }
    float z[8];
#pragma unroll
    for (int jo = 0; jo < 8; ++jo) {
        float a = bl[jo];
#pragma unroll
        for (int j = 0; j < 16; ++j) a = fmaf(hv[j], Wl[j * 8 + jo], a);
        z[jo] = a;
    }
    if (act) {
        float4* zr = (float4*)(zsum + (size_t)r * 8);
        float4 z0 = zr[0], z1 = zr[1];
        zr[0] = make_float4(z0.x + z[0], z0.y + z[1], z0.z + z[2], z0.w + z[3]);
        zr[1] = make_float4(z1.x + z[4], z1.y + z[5], z1.z + z[6], z1.w + z[7]);
    }
    pool_max(z, act, batch[r], pool, threadIdx.x & 63);
}

// -------- layer 2 apply --------
extern "C" __global__ void __launch_bounds__(256)
k_apply2(const float* __restrict__ pre, const float* __restrict__ sb,
         const float* __restrict__ Wl, const float* __restrict__ bl,
         const int* __restrict__ batch, float* __restrict__ hout,
         float* __restrict__ zsum, unsigned* __restrict__ pool) {
    int r0 = blockIdx.x * 256 + threadIdx.x;
    bool act = r0 < GN;
    int r = act ? r0 : (GN - 1);
    const float4* pr = (const float4*)(pre + (size_t)r * 8);
    float4 p0 = pr[0], p1 = pr[1];
    float pv[8] = {p0.x, p0.y, p0.z, p0.w, p1.x, p1.y, p1.z, p1.w};
    float hv[8];
#pragma unroll
    for (int j = 0; j < 8; ++j) hv[j] = fmaf(pv[j], sb[j], sb[8 + j]);
    if (act) {
        float4* hr = (float4*)(hout + (size_t)r * 8);
        hr[0] = make_float4(hv[0], hv[1], hv[2], hv[3]);
        hr[1] = make_float4(hv[4], hv[5], hv[6], hv[7]);
    }
    float z[8];
#pragma unroll
    for (int jo = 0; jo < 8; ++jo) {
        float a = bl[jo];
#pragma unroll
        for (int j = 0; j < 8; ++j) a = fmaf(hv[j], Wl[j * 8 + jo], a);
        z[jo] = a;
    }
    if (act) {
        float4* zr = (float4*)(zsum + (size_t)r * 8);
        float4 z0 = zr[0], z1 = zr[1];
        zr[0] = make_float4(z0.x + z[0], z0.y + z[1], z0.z + z[2], z0.w + z[3]);
        zr[1] = make_float4(z1.x + z[4], z1.y + z[5], z1.z + z[6], z1.w + z[7]);
    }
    pool_max(z, act, batch[r], pool, threadIdx.x & 63);
}

// -------- final: out = pool0 + pool1 + pool2 --------
extern "C" __global__ void k_out(const unsigned* __restrict__ pools,
                                 float* __restrict__ out) {
    int i = threadIdx.x;
    if (i < 128)
        out[i] = funmap(pools[i]) + funmap(pools[128 + i]) + funmap(pools[256 + i]);
}

extern "C" void kernel_launch(void* const* d_in, const int* in_sizes, int n_in,
                              void* d_out, int out_size, void* d_ws, size_t ws_size,
                              hipStream_t stream) {
    const float* x   = (const float*)d_in[0];
    const int* ei    = (const int*)d_in[1];
    const int* batch = (const int*)d_in[2];
    const float* W0  = (const float*)d_in[3];
    const float* b0  = (const float*)d_in[4];
    const float* g0  = (const float*)d_in[5];
    const float* be0 = (const float*)d_in[6];
    const float* Wl0 = (const float*)d_in[7];
    const float* bl0 = (const float*)d_in[8];
    const float* W1  = (const float*)d_in[9];
    const float* b1  = (const float*)d_in[10];
    const float* g1  = (const float*)d_in[11];
    const float* be1 = (const float*)d_in[12];
    const float* Wl1 = (const float*)d_in[13];
    const float* bl1 = (const float*)d_in[14];
    const float* W2  = (const float*)d_in[15];
    const float* b2  = (const float*)d_in[16];
    const float* g2  = (const float*)d_in[17];
    const float* be2 = (const float*)d_in[18];
    const float* Wl2 = (const float*)d_in[19];
    const float* bl2 = (const float*)d_in[20];

    const int* src = ei;
    const int* dst = ei + GE;

    char* ws = (char*)d_ws;
    double* stats0  = (double*)(ws + 0);
    double* stats1  = (double*)(ws + 256);
    double* stats2  = (double*)(ws + 512);
    float* sb0      = (float*)(ws + 640);
    float* sb1      = (float*)(ws + 768);
    float* sb2      = (float*)(ws + 896);
    unsigned* pools = (unsigned*)(ws + 960);

    float* out  = (float*)d_out;
    float* zsum = out + 128;
    float* hout = out + 128 + GN * GDT;

    int nb = (GN + 255) / 256;  // 391
    bool fast = ws_size >= FAST_NEED;

    if (fast) {
        unsigned* gcursor = (unsigned*)(ws + 2560);
        unsigned* bins    = (unsigned*)(ws + 8192);
        float* pre  = (float*)(ws + 15648256);
        float* hbuf = (float*)(ws + 22048256);

        hipLaunchKernelGGL(k_init, dim3(1), dim3(512), 0, stream, stats0, pools, gcursor);
        hipLaunchKernelGGL(k_scatter, dim3(EBLK), dim3(256), 0, stream, src, dst, gcursor, bins);
        // layer 0
        hipLaunchKernelGGL(k_gemm0, dim3(nb), dim3(256), 0, stream, x, W0, b0, pre, stats0);
        hipLaunchKernelGGL(k_stats, dim3(1), dim3(32), 0, stream, stats0, g0, be0, sb0, 16);
        hipLaunchKernelGGL(k_apply0, dim3(nb), dim3(256), 0, stream,
                           pre, sb0, Wl0, bl0, batch, hbuf, zsum, pools);
        // layer 1: fused agg + GEMM
        hipLaunchKernelGGL((k_agggemm<16>), dim3(NBK), dim3(512), 0, stream,
                           hbuf, gcursor, bins, W1, b1, pre, stats1);
        hipLaunchKernelGGL(k_stats, dim3(1), dim3(32), 0, stream, stats1, g1, be1, sb1, 16);
        hipLaunchKernelGGL(k_apply1, dim3(nb), dim3(256), 0, stream,
                           pre, sb1, Wl1, bl1, batch, hbuf, zsum, pools + 128);
        // layer 2: fused agg + GEMM
        hipLaunchKernelGGL((k_agggemm<8>), dim3(NBK), dim3(512), 0, stream,
                           hbuf, gcursor, bins, W2, b2, pre, stats2);
        hipLaunchKernelGGL(k_stats, dim3(1), dim3(32), 0, stream, stats2, g2, be2, sb2, 8);
        hipLaunchKernelGGL(k_apply2, dim3(nb), dim3(256), 0, stream,
                           pre, sb2, Wl2, bl2, batch, hout, zsum, pools + 256);
        hipLaunchKernelGGL(k_out, dim3(1), dim3(128), 0, stream, pools, out);
    } else {
        // round-1 proven fallback (global-atomic aggregation), ~19.2 MB ws
        float* pre  = (float*)(ws + 4096);
        float* hbuf = (float*)(ws + 4096 + 6400000);
        float* agg  = (float*)(ws + 4096 + 12800000);
        int eb = (GE + 255) / 256;

        hipLaunchKernelGGL(k_init, dim3(1), dim3(512), 0, stream, stats0, pools, (unsigned*)pre);
        hipLaunchKernelGGL(k_gemm0, dim3(nb), dim3(256), 0, stream, x, W0, b0, pre, stats0);
        hipLaunchKernelGGL(k_stats, dim3(1), dim3(32), 0, stream, stats0, g0, be0, sb0, 16);
        hipLaunchKernelGGL(k_apply0, dim3(nb), dim3(256), 0, stream,
                           pre, sb0, Wl0, bl0, batch, hbuf, zsum, pools);
        hipLaunchKernelGGL(k_zero, dim3(6250), dim3(256), 0, stream, agg, GN * 16);
        hipLaunchKernelGGL(k_edge, dim3(eb), dim3(256), 0, stream, src, dst, hbuf, agg);
        hipLaunchKernelGGL(k_hadd, dim3(6250), dim3(256), 0, stream, hbuf, agg);
        hipLaunchKernelGGL(k_gemm1, dim3(nb), dim3(256), 0, stream, hbuf, W1, b1, pre, stats1);
        hipLaunchKernelGGL(k_stats, dim3(1), dim3(32), 0, stream, stats1, g1, be1, sb1, 16);
        hipLaunchKernelGGL(k_apply1, dim3(nb), dim3(256), 0, stream,
                           pre, sb1, Wl1, bl1, batch, hbuf, zsum, pools + 128);
        hipLaunchKernelGGL(k_zero, dim3(6250), dim3(256), 0, stream, agg, GN * 16);
        hipLaunchKernelGGL(k_edge, dim3(eb), dim3(256), 0, stream, src, dst, hbuf, agg);
        hipLaunchKernelGGL(k_hadd, dim3(6250), dim3(256), 0, stream, hbuf, agg);
        hipLaunchKernelGGL(k_gemm2, dim3(nb), dim3(256), 0, stream, hbuf, W2, b2, pre, stats2);
        hipLaunchKernelGGL(k_stats, dim3(1), dim3(32), 0, stream, stats2, g2, be2, sb2, 8);
        hipLaunchKernelGGL(k_apply2, dim3(nb), dim3(256), 0, stream,
                           pre, sb2, Wl2, bl2, batch, hout, zsum, pools + 256);
        hipLaunchKernelGGL(k_out, dim3(1), dim3(128), 0, stream, pools, out);
    }
}